// Round 6
// baseline (4750.044 us; speedup 1.0000x reference)
//
#include <hip/hip_runtime.h>
#include <hip/hip_fp16.h>

#define N 4096
#define KX 3072
#define KZ 128
#define NB (N / 64)
#define NTRI (NB * (NB + 1) / 2)

// ---------- helpers ----------
__device__ __forceinline__ float2 up2(unsigned v) {
  __half2 h = __builtin_bit_cast(__half2, v);
  return __half22float2(h);
}

// DPP-based partial min (within 16-lane rows); CTRL is a compile-time constant.
template <int CTRL>
__device__ __forceinline__ float dpp_fmin(float x) {
  int y = __builtin_amdgcn_update_dpp(0, __float_as_int(x), CTRL, 0xF, 0xF, true);
  return fminf(x, __int_as_float(y));
}

// xor-16 / xor-32 butterfly min. NOTE: deliberately ds_swizzle + shfl (round-4
// proven). The permlane{16,32}_swap builtins are suspected of a dual-def
// codegen hazard when combined with in-flight global loads (round-5 post-timing
// nondeterminism) — do not reintroduce without isolated verification.
__device__ __forceinline__ float xmin16(float x) {
  int t = __builtin_amdgcn_ds_swizzle(__float_as_int(x), 0x401F);  // xor 16
  return fminf(x, __int_as_float(t));
}
__device__ __forceinline__ float xmin32(float x) {
  return fminf(x, __shfl_xor(x, 32));
}

// ---------- row squared norms ----------
__global__ __launch_bounds__(256) void sqnorm_kernel(const float* __restrict__ X, int K,
                                                     float* __restrict__ sq) {
  int row = blockIdx.x;
  const float4* xr = (const float4*)(X + (size_t)row * K);
  float s = 0.f;
  int n4 = K >> 2;
  for (int i = threadIdx.x; i < n4; i += 256) {
    float4 v = xr[i];
    s += v.x * v.x + v.y * v.y + v.z * v.z + v.w * v.w;
  }
  for (int off = 32; off > 0; off >>= 1) s += __shfl_down(s, off);
  __shared__ float wsum[4];
  int lane = threadIdx.x & 63, w = threadIdx.x >> 6;
  if (lane == 0) wsum[w] = s;
  __syncthreads();
  if (threadIdx.x == 0) {
    float t = 0.f;
    #pragma unroll
    for (int i = 0; i < 4; ++i) t += wsum[i];
    sq[row] = t;
  }
}

// ---------- fused distance GEMM: D = sqrt(relu(sq_i + sq_j - 2*X@X^T)), half out ----------
__global__ __launch_bounds__(256) void dist_gemm_kernel(const float* __restrict__ X, int K,
                                                        const float* __restrict__ sq,
                                                        __half* __restrict__ D) {
  int t = blockIdx.x;
  int br = (int)((sqrtf(8.0f * (float)t + 1.0f) - 1.0f) * 0.5f);
  while ((br + 1) * (br + 2) / 2 <= t) ++br;
  while (br * (br + 1) / 2 > t) --br;
  int bc = t - br * (br + 1) / 2;
  int i0 = br * 64, j0 = bc * 64;

  __shared__ float As[32][68];
  __shared__ float Bs[32][68];

  int tid = threadIdx.x;
  int tx = tid & 15, ty = tid >> 4;

  float acc[4][4] = {};

  for (int k0 = 0; k0 < K; k0 += 32) {
    #pragma unroll
    for (int u = 0; u < 2; ++u) {
      int f = tid + u * 256;   // 0..511
      int m = f >> 3;          // 0..63
      int kc = (f & 7) * 4;    // 0..28
      float4 a = *(const float4*)(X + (size_t)(i0 + m) * K + k0 + kc);
      As[kc + 0][m] = a.x; As[kc + 1][m] = a.y; As[kc + 2][m] = a.z; As[kc + 3][m] = a.w;
      float4 b = *(const float4*)(X + (size_t)(j0 + m) * K + k0 + kc);
      Bs[kc + 0][m] = b.x; Bs[kc + 1][m] = b.y; Bs[kc + 2][m] = b.z; Bs[kc + 3][m] = b.w;
    }
    __syncthreads();
    #pragma unroll
    for (int kk = 0; kk < 32; ++kk) {
      float4 a = *(const float4*)&As[kk][ty * 4];
      float4 b = *(const float4*)&Bs[kk][tx * 4];
      float av[4] = {a.x, a.y, a.z, a.w};
      float bv[4] = {b.x, b.y, b.z, b.w};
      #pragma unroll
      for (int i = 0; i < 4; ++i)
        #pragma unroll
        for (int j = 0; j < 4; ++j)
          acc[i][j] = fmaf(av[i], bv[j], acc[i][j]);
    }
    __syncthreads();
  }

  #pragma unroll
  for (int i = 0; i < 4; ++i) {
    int gi = i0 + ty * 4 + i;
    float sqi = sq[gi];
    #pragma unroll
    for (int j = 0; j < 4; ++j) {
      int gj = j0 + tx * 4 + j;
      float d2 = sqi + sq[gj] - 2.0f * acc[i][j];
      float d = sqrtf(fmaxf(d2, 0.0f));
      __half h = __float2half(d);
      D[(size_t)gi * N + gj] = h;
      D[(size_t)gj * N + gi] = h;
    }
  }
}

// ---------- MST (exact replication of the reference scan) ----------
// block 0 -> Dx, block 1 -> Dz. 512 threads (8 waves), 8 nodes/thread, ALL state
// in named scalars. Wave reduce: 4 DPP + ds_swizzle(xor16) + shfl_xor(32) on
// the VALUE, ballot picks the lowest lane (= lowest node index on ties).
// Speculation: the cross-wave combine tracks best AND second-best slot keys;
// the second-best index is the predicted next j. Its row is loaded into
// registers each step; on a correct prediction the next step skips the global
// load entirely (wave-uniform branch), on a miss semantics are unchanged.
__global__ __launch_bounds__(512) void mst_kernel(const __half* __restrict__ Dx,
                                                  const __half* __restrict__ Dz,
                                                  int2* __restrict__ ex,
                                                  int2* __restrict__ ez) {
  const __half* __restrict__ D = (blockIdx.x == 0) ? Dx : Dz;
  int2* __restrict__ edges = (blockIdx.x == 0) ? ex : ez;
  const float INF = __builtin_inff();

  int tid = threadIdx.x;      // 0..511
  int lane = tid & 63;
  int w = tid >> 6;           // wave 0..7
  int base = tid * 8;         // nodes [base, base+8)

  float md0, md1, md2, md3, md4, md5, md6, md7;
  int par0 = 0, par1 = 0, par2 = 0, par3 = 0, par4 = 0, par5 = 0, par6 = 0, par7 = 0;
  {
    uint4 u = *(const uint4*)(D + base);
    float2 f;
    f = up2(u.x); md0 = f.x; md1 = f.y;
    f = up2(u.y); md2 = f.x; md3 = f.y;
    f = up2(u.z); md4 = f.x; md5 = f.y;
    f = up2(u.w); md6 = f.x; md7 = f.y;
  }
  if (tid == 0) md0 = INF;  // node 0 starts in tree

  __shared__ unsigned long long skey[2][8];

  int jpred = -1;
  uint4 pf = make_uint4(0, 0, 0, 0);

  for (int step = 0; step < N - 1; ++step) {
    // ---- local argmin over 8 named scalars (exact lowest-index tiebreak)
    bool c;
    c = md1 < md0; float v01 = c ? md1 : md0; int i01 = c ? 1 : 0;
    c = md3 < md2; float v23 = c ? md3 : md2; int i23 = c ? 3 : 2;
    c = md5 < md4; float v45 = c ? md5 : md4; int i45 = c ? 5 : 4;
    c = md7 < md6; float v67 = c ? md7 : md6; int i67 = c ? 7 : 6;
    c = v23 < v01; float v03 = c ? v23 : v01; int i03 = c ? i23 : i01;
    c = v67 < v45; float v47 = c ? v67 : v45; int i47 = c ? i67 : i45;
    c = v47 < v03; float bv = c ? v47 : v03;  int bi = base + (c ? i47 : i03);

    // ---- wave-wide min of the value
    float mv = bv;
    mv = dpp_fmin<0xB1>(mv);    // quad_perm [1,0,3,2]  : xor 1
    mv = dpp_fmin<0x4E>(mv);    // quad_perm [2,3,0,1]  : xor 2
    mv = dpp_fmin<0x141>(mv);   // row_half_mirror      : xor 4
    mv = dpp_fmin<0x140>(mv);   // row_mirror           : xor 8
    mv = xmin16(mv);            // xor 16 (ds_swizzle)
    mv = xmin32(mv);            // xor 32 (shfl)

    // lowest lane holding the min == lowest node index (lane order = index order)
    unsigned long long ball = __ballot(bv == mv);
    int first = __ffsll(ball) - 1;
    int p = step & 1;
    if (lane == first)
      skey[p][w] = ((unsigned long long)__float_as_uint(mv) << 32) | (unsigned)bi;
    __syncthreads();

    // ---- cross-wave combine: best + second-best over 8 u64 slot keys
    unsigned long long kb = skey[p][0];
    unsigned long long k2 = skey[p][1];
    if (k2 < kb) { unsigned long long t = kb; kb = k2; k2 = t; }
    #pragma unroll
    for (int k = 2; k < 8; ++k) {
      unsigned long long o = skey[p][k];
      if (o < kb) { k2 = kb; kb = o; }
      else if (o < k2) { k2 = o; }
    }
    int j = (int)(unsigned)kb;
    int jn = (int)(unsigned)k2;   // predicted next selection
    int jt = j >> 3, jl = j & 7;

    // ---- row values: speculation hit -> registers, miss -> global load.
    // Condition is wave-uniform; on hit s_cbranch_execz skips the load.
    uint4 u;
    if (j == jpred) {
      u = pf;
    } else {
      u = *(const uint4*)(D + (size_t)j * N + base);
    }
    // issue next step's speculative row load (overlaps update + reduce + barrier)
    pf = *(const uint4*)(D + (size_t)jn * N + base);
    jpred = jn;

    // record edge with parent BEFORE this step's updates (matches reference)
    if (jt == tid) {
      int pj = (jl == 0) ? par0 : (jl == 1) ? par1 : (jl == 2) ? par2 :
               (jl == 3) ? par3 : (jl == 4) ? par4 : (jl == 5) ? par5 :
               (jl == 6) ? par6 : par7;
      edges[step] = make_int2(pj, j);
    }

    // ---- convert + min-update (all static, named scalars)
    float2 f;
    float r0, r1, r2, r3, r4, r5, r6, r7;
    f = up2(u.x); r0 = f.x; r1 = f.y;
    f = up2(u.y); r2 = f.x; r3 = f.y;
    f = up2(u.z); r4 = f.x; r5 = f.y;
    f = up2(u.w); r6 = f.x; r7 = f.y;

    #define UPD(q, rq) { bool up = rq < md##q; md##q = up ? rq : md##q; par##q = up ? j : par##q; }
    UPD(0, r0) UPD(1, r1) UPD(2, r2) UPD(3, r3)
    UPD(4, r4) UPD(5, r5) UPD(6, r6) UPD(7, r7)
    #undef UPD

    // md[jl] = INF after min-update (matches .at[j].set(inf))
    if (jt == tid) {
      if      (jl == 0) md0 = INF;
      else if (jl == 1) md1 = INF;
      else if (jl == 2) md2 = INF;
      else if (jl == 3) md3 = INF;
      else if (jl == 4) md4 = INF;
      else if (jl == 5) md5 = INF;
      else if (jl == 6) md6 = INF;
      else              md7 = INF;
    }
  }
}

// ---------- final loss ----------
__global__ __launch_bounds__(1024) void loss_kernel(const __half* __restrict__ Dx,
                                                    const __half* __restrict__ Dz,
                                                    const int2* __restrict__ ex,
                                                    const int2* __restrict__ ez,
                                                    float* __restrict__ out) {
  int tid = threadIdx.x;
  float s = 0.f;
  const int M = N - 1;
  for (int e = tid; e < 2 * M; e += 1024) {
    int2 uv = (e < M) ? ex[e] : ez[e - M];
    size_t off = (size_t)uv.x * N + uv.y;
    float dx = __half2float(Dx[off]);
    float dz = __half2float(Dz[off]);
    float d = dx - dz;
    s += d * d;
  }
  for (int off = 32; off > 0; off >>= 1) s += __shfl_down(s, off);
  __shared__ float wsum[16];
  int lane = tid & 63, w = tid >> 6;
  if (lane == 0) wsum[w] = s;
  __syncthreads();
  if (tid == 0) {
    float t = 0.f;
    #pragma unroll
    for (int i = 0; i < 16; ++i) t += wsum[i];
    out[0] = 0.5f * t;
  }
}

// ---------- launch ----------
extern "C" void kernel_launch(void* const* d_in, const int* in_sizes, int n_in,
                              void* d_out, int out_size, void* d_ws, size_t ws_size,
                              hipStream_t stream) {
  const float* x = (const float*)d_in[0];
  const float* z = (const float*)d_in[1];
  float* out = (float*)d_out;
  char* ws = (char*)d_ws;

  __half* Dx = (__half*)ws;
  __half* Dz = Dx + (size_t)N * N;
  float* sqx = (float*)(Dz + (size_t)N * N);
  float* sqz = sqx + N;
  int2* ex = (int2*)(sqz + N);
  int2* ez = ex + (N - 1);

  sqnorm_kernel<<<N, 256, 0, stream>>>(x, KX, sqx);
  sqnorm_kernel<<<N, 256, 0, stream>>>(z, KZ, sqz);
  dist_gemm_kernel<<<NTRI, 256, 0, stream>>>(x, KX, sqx, Dx);
  dist_gemm_kernel<<<NTRI, 256, 0, stream>>>(z, KZ, sqz, Dz);
  mst_kernel<<<2, 512, 0, stream>>>(Dx, Dz, ex, ez);
  loss_kernel<<<1, 1024, 0, stream>>>(Dx, Dz, ex, ez, out);
}

// Round 7
// 3655.368 us; speedup vs baseline: 1.2995x; 1.2995x over previous
//
#include <hip/hip_runtime.h>
#include <hip/hip_fp16.h>

#define N 4096
#define KX 3072
#define KZ 128
#define NBT (N / 128)               // 32 tile-rows for the MFMA dist kernel
#define NTRI2 (NBT * (NBT + 1) / 2) // 528 triangular tiles

typedef __attribute__((ext_vector_type(8))) short bf16x8;
typedef __attribute__((ext_vector_type(4))) float f32x4;

// ---------- helpers ----------
__device__ __forceinline__ float2 up2(unsigned v) {
  __half2 h = __builtin_bit_cast(__half2, v);
  return __half22float2(h);
}

__device__ __forceinline__ short f2bf(float f) {  // RTN-even fp32 -> bf16
  unsigned u = __float_as_uint(f);
  u += 0x7fffu + ((u >> 16) & 1u);
  return (short)(u >> 16);
}

// DPP-based partial min (within 16-lane rows); CTRL is a compile-time constant.
template <int CTRL>
__device__ __forceinline__ float dpp_fmin(float x) {
  int y = __builtin_amdgcn_update_dpp(0, __float_as_int(x), CTRL, 0xF, 0xF, true);
  return fminf(x, __int_as_float(y));
}
__device__ __forceinline__ float xmin16(float x) {
  int t = __builtin_amdgcn_ds_swizzle(__float_as_int(x), 0x401F);  // xor 16
  return fminf(x, __int_as_float(t));
}
__device__ __forceinline__ float xmin32(float x) {
  return fminf(x, __shfl_xor(x, 32));
}

// ---------- fp32 -> bf16 conversion (8 elems/thread, grid-stride) ----------
__global__ __launch_bounds__(256) void cvt_bf16_kernel(const float* __restrict__ X,
                                                       short* __restrict__ Xb, int n8) {
  int stride = gridDim.x * 256;
  for (int i = blockIdx.x * 256 + threadIdx.x; i < n8; i += stride) {
    float4 a = *(const float4*)(X + (size_t)i * 8);
    float4 b = *(const float4*)(X + (size_t)i * 8 + 4);
    bf16x8 o;
    o[0] = f2bf(a.x); o[1] = f2bf(a.y); o[2] = f2bf(a.z); o[3] = f2bf(a.w);
    o[4] = f2bf(b.x); o[5] = f2bf(b.y); o[6] = f2bf(b.z); o[7] = f2bf(b.w);
    *(bf16x8*)(Xb + (size_t)i * 8) = o;
  }
}

// ---------- row squared norms (exact fp32) ----------
__global__ __launch_bounds__(256) void sqnorm_kernel(const float* __restrict__ X, int K,
                                                     float* __restrict__ sq) {
  int row = blockIdx.x;
  const float4* xr = (const float4*)(X + (size_t)row * K);
  float s = 0.f;
  int n4 = K >> 2;
  for (int i = threadIdx.x; i < n4; i += 256) {
    float4 v = xr[i];
    s += v.x * v.x + v.y * v.y + v.z * v.z + v.w * v.w;
  }
  for (int off = 32; off > 0; off >>= 1) s += __shfl_down(s, off);
  __shared__ float wsum[4];
  int lane = threadIdx.x & 63, w = threadIdx.x >> 6;
  if (lane == 0) wsum[w] = s;
  __syncthreads();
  if (threadIdx.x == 0) {
    float t = 0.f;
    #pragma unroll
    for (int i = 0; i < 4; ++i) t += wsum[i];
    sq[row] = t;
  }
}

// ---------- MFMA bf16 distance GEMM ----------
// C = Xb * Xb^T (bf16 inputs, fp32 acc), fused D = sqrt(relu(sq_i + sq_j - 2C)),
// half output, triangular 128x128 tiles (mirror-written). 256 thr = 4 waves in
// 2x2; each wave owns a 64x64 quadrant = 4x4 fragments of 16x16x32 MFMA.
// LDS row stride 40 shorts: 80 B = 16-B aligned, <=2-way bank conflicts.
__global__ __launch_bounds__(256) void dist_mfma_kernel(const short* __restrict__ Xb, int K,
                                                        const float* __restrict__ sq,
                                                        __half* __restrict__ D) {
  int t = blockIdx.x;
  int br = (int)((sqrtf(8.0f * (float)t + 1.0f) - 1.0f) * 0.5f);
  while ((br + 1) * (br + 2) / 2 <= t) ++br;
  while (br * (br + 1) / 2 > t) --br;
  int bc = t - br * (br + 1) / 2;
  int i0 = br * 128, j0 = bc * 128;

  __shared__ short As[128][40];
  __shared__ short Bs[128][40];

  int tid = threadIdx.x, lane = tid & 63, w = tid >> 6;
  int wr = w >> 1, wc = w & 1;       // wave quadrant (2x2 of 64x64)
  int fr = lane & 15, fc = lane >> 4; // fragment row/col, k-chunk

  f32x4 acc[4][4];
  #pragma unroll
  for (int m = 0; m < 4; ++m)
    #pragma unroll
    for (int nn = 0; nn < 4; ++nn)
      acc[m][nn] = (f32x4){0.f, 0.f, 0.f, 0.f};

  for (int k0 = 0; k0 < K; k0 += 32) {
    #pragma unroll
    for (int u = 0; u < 2; ++u) {
      int f = tid + u * 256;   // 0..511
      int r = f >> 2;          // 0..127
      int c = (f & 3) * 8;     // 0,8,16,24
      *(bf16x8*)&As[r][c] = *(const bf16x8*)(Xb + (size_t)(i0 + r) * K + k0 + c);
      *(bf16x8*)&Bs[r][c] = *(const bf16x8*)(Xb + (size_t)(j0 + r) * K + k0 + c);
    }
    __syncthreads();
    bf16x8 af[4], bg[4];
    #pragma unroll
    for (int m = 0; m < 4; ++m)
      af[m] = *(const bf16x8*)&As[wr * 64 + m * 16 + fr][fc * 8];
    #pragma unroll
    for (int nn = 0; nn < 4; ++nn)
      bg[nn] = *(const bf16x8*)&Bs[wc * 64 + nn * 16 + fr][fc * 8];
    #pragma unroll
    for (int m = 0; m < 4; ++m)
      #pragma unroll
      for (int nn = 0; nn < 4; ++nn)
        acc[m][nn] = __builtin_amdgcn_mfma_f32_16x16x32_bf16(af[m], bg[nn], acc[m][nn], 0, 0, 0);
    __syncthreads();
  }

  // epilogue: C/D mapping col = lane&15, row = (lane>>4)*4 + reg (m89-verified)
  #pragma unroll
  for (int m = 0; m < 4; ++m) {
    #pragma unroll
    for (int nn = 0; nn < 4; ++nn) {
      int gj = j0 + wc * 64 + nn * 16 + fr;
      float sqj = sq[gj];
      #pragma unroll
      for (int e = 0; e < 4; ++e) {
        int gi = i0 + wr * 64 + m * 16 + fc * 4 + e;
        float d2 = sq[gi] + sqj - 2.0f * acc[m][nn][e];
        float d = sqrtf(fmaxf(d2, 0.0f));
        __half h = __float2half(d);
        D[(size_t)gi * N + gj] = h;
        D[(size_t)gj * N + gi] = h;
      }
    }
  }
}

// ---------- MST (exact replication of the reference scan; round-4 proven) ----------
// block 0 -> Dx, block 1 -> Dz. 512 threads (8 waves), 8 nodes/thread, ALL state
// in named scalars. Wave reduce: 4 DPP + ds_swizzle(xor16) + shfl_xor(32) on
// the VALUE, ballot picks the lowest lane (= lowest node index on ties).
// NOTE: runner-up row speculation was tried (round 6) and REGRESSED (+12%,
// FETCH 41->70 MB) — do not reintroduce.
__global__ __launch_bounds__(512) void mst_kernel(const __half* __restrict__ Dx,
                                                  const __half* __restrict__ Dz,
                                                  int2* __restrict__ ex,
                                                  int2* __restrict__ ez) {
  const __half* __restrict__ D = (blockIdx.x == 0) ? Dx : Dz;
  int2* __restrict__ edges = (blockIdx.x == 0) ? ex : ez;
  const float INF = __builtin_inff();

  int tid = threadIdx.x;      // 0..511
  int lane = tid & 63;
  int w = tid >> 6;           // wave 0..7
  int base = tid * 8;         // nodes [base, base+8)

  float md0, md1, md2, md3, md4, md5, md6, md7;
  int par0 = 0, par1 = 0, par2 = 0, par3 = 0, par4 = 0, par5 = 0, par6 = 0, par7 = 0;
  {
    uint4 u = *(const uint4*)(D + base);
    float2 f;
    f = up2(u.x); md0 = f.x; md1 = f.y;
    f = up2(u.y); md2 = f.x; md3 = f.y;
    f = up2(u.z); md4 = f.x; md5 = f.y;
    f = up2(u.w); md6 = f.x; md7 = f.y;
  }
  if (tid == 0) md0 = INF;  // node 0 starts in tree

  __shared__ unsigned long long skey[2][8];

  for (int step = 0; step < N - 1; ++step) {
    // ---- local argmin over 8 named scalars (exact lowest-index tiebreak)
    bool c;
    c = md1 < md0; float v01 = c ? md1 : md0; int i01 = c ? 1 : 0;
    c = md3 < md2; float v23 = c ? md3 : md2; int i23 = c ? 3 : 2;
    c = md5 < md4; float v45 = c ? md5 : md4; int i45 = c ? 5 : 4;
    c = md7 < md6; float v67 = c ? md7 : md6; int i67 = c ? 7 : 6;
    c = v23 < v01; float v03 = c ? v23 : v01; int i03 = c ? i23 : i01;
    c = v67 < v45; float v47 = c ? v67 : v45; int i47 = c ? i67 : i45;
    c = v47 < v03; float bv = c ? v47 : v03;  int bi = base + (c ? i47 : i03);

    // ---- wave-wide min of the value
    float mv = bv;
    mv = dpp_fmin<0xB1>(mv);    // quad_perm [1,0,3,2]  : xor 1
    mv = dpp_fmin<0x4E>(mv);    // quad_perm [2,3,0,1]  : xor 2
    mv = dpp_fmin<0x141>(mv);   // row_half_mirror      : xor 4
    mv = dpp_fmin<0x140>(mv);   // row_mirror           : xor 8
    mv = xmin16(mv);            // xor 16 (ds_swizzle)
    mv = xmin32(mv);            // xor 32 (shfl)

    // lowest lane holding the min == lowest node index (lane order = index order)
    unsigned long long ball = __ballot(bv == mv);
    int first = __ffsll(ball) - 1;
    int p = step & 1;
    if (lane == first)
      skey[p][w] = ((unsigned long long)__float_as_uint(mv) << 32) | (unsigned)bi;
    __syncthreads();

    // ---- cross-wave combine: u64 min over 8 slots (ties -> lowest index)
    unsigned long long key = skey[p][0];
    #pragma unroll
    for (int k = 1; k < 8; ++k) {
      unsigned long long o = skey[p][k];
      key = (o < key) ? o : key;
    }
    int j = (int)(unsigned)key;
    int jt = j >> 3, jl = j & 7;

    // record edge with parent BEFORE this step's updates (matches reference)
    if (jt == tid) {
      int pj = (jl == 0) ? par0 : (jl == 1) ? par1 : (jl == 2) ? par2 :
               (jl == 3) ? par3 : (jl == 4) ? par4 : (jl == 5) ? par5 :
               (jl == 6) ? par6 : par7;
      edges[step] = make_int2(pj, j);
    }

    // ---- load row j (16 B/thread, coalesced, half) and min-update
    uint4 u = *(const uint4*)(D + (size_t)j * N + base);
    float2 f;
    float r0, r1, r2, r3, r4, r5, r6, r7;
    f = up2(u.x); r0 = f.x; r1 = f.y;
    f = up2(u.y); r2 = f.x; r3 = f.y;
    f = up2(u.z); r4 = f.x; r5 = f.y;
    f = up2(u.w); r6 = f.x; r7 = f.y;

    #define UPD(q, rq) { bool up = rq < md##q; md##q = up ? rq : md##q; par##q = up ? j : par##q; }
    UPD(0, r0) UPD(1, r1) UPD(2, r2) UPD(3, r3)
    UPD(4, r4) UPD(5, r5) UPD(6, r6) UPD(7, r7)
    #undef UPD

    // md[jl] = INF after min-update (matches .at[j].set(inf))
    if (jt == tid) {
      if      (jl == 0) md0 = INF;
      else if (jl == 1) md1 = INF;
      else if (jl == 2) md2 = INF;
      else if (jl == 3) md3 = INF;
      else if (jl == 4) md4 = INF;
      else if (jl == 5) md5 = INF;
      else if (jl == 6) md6 = INF;
      else              md7 = INF;
    }
  }
}

// ---------- final loss ----------
__global__ __launch_bounds__(1024) void loss_kernel(const __half* __restrict__ Dx,
                                                    const __half* __restrict__ Dz,
                                                    const int2* __restrict__ ex,
                                                    const int2* __restrict__ ez,
                                                    float* __restrict__ out) {
  int tid = threadIdx.x;
  float s = 0.f;
  const int M = N - 1;
  for (int e = tid; e < 2 * M; e += 1024) {
    int2 uv = (e < M) ? ex[e] : ez[e - M];
    size_t off = (size_t)uv.x * N + uv.y;
    float dx = __half2float(Dx[off]);
    float dz = __half2float(Dz[off]);
    float d = dx - dz;
    s += d * d;
  }
  for (int off = 32; off > 0; off >>= 1) s += __shfl_down(s, off);
  __shared__ float wsum[16];
  int lane = tid & 63, w = tid >> 6;
  if (lane == 0) wsum[w] = s;
  __syncthreads();
  if (tid == 0) {
    float t = 0.f;
    #pragma unroll
    for (int i = 0; i < 16; ++i) t += wsum[i];
    out[0] = 0.5f * t;
  }
}

// ---------- launch ----------
extern "C" void kernel_launch(void* const* d_in, const int* in_sizes, int n_in,
                              void* d_out, int out_size, void* d_ws, size_t ws_size,
                              hipStream_t stream) {
  const float* x = (const float*)d_in[0];
  const float* z = (const float*)d_in[1];
  float* out = (float*)d_out;
  char* ws = (char*)d_ws;

  __half* Dx = (__half*)ws;                       // 32 MB
  __half* Dz = Dx + (size_t)N * N;                // 32 MB
  short* Xb = (short*)(Dz + (size_t)N * N);       // 24 MB
  short* Zb = Xb + (size_t)N * KX;                // 1 MB
  float* sqx = (float*)(Zb + (size_t)N * KZ);
  float* sqz = sqx + N;
  int2* ex = (int2*)(sqz + N);
  int2* ez = ex + (N - 1);

  cvt_bf16_kernel<<<2048, 256, 0, stream>>>(x, Xb, N * KX / 8);
  cvt_bf16_kernel<<<256, 256, 0, stream>>>(z, Zb, N * KZ / 8);
  sqnorm_kernel<<<N, 256, 0, stream>>>(x, KX, sqx);
  sqnorm_kernel<<<N, 256, 0, stream>>>(z, KZ, sqz);
  dist_mfma_kernel<<<NTRI2, 256, 0, stream>>>(Xb, KX, sqx, Dx);
  dist_mfma_kernel<<<NTRI2, 256, 0, stream>>>(Zb, KZ, sqz, Dz);
  mst_kernel<<<2, 512, 0, stream>>>(Dx, Dz, ex, ez);
  loss_kernel<<<1, 1024, 0, stream>>>(Dx, Dz, ex, ez, out);
}